// Round 2
// baseline (1335.072 us; speedup 1.0000x reference)
//
#include <hip/hip_runtime.h>
#include <hip/hip_bf16.h>

typedef unsigned short u16;
typedef __attribute__((ext_vector_type(8))) short short8x;
typedef __attribute__((ext_vector_type(4))) float f32x4;
typedef __bf16 bf16x8 __attribute__((ext_vector_type(8)));

#define SCALE 0.17677669529663687f

__device__ __forceinline__ u16 f2bf(float f) {
  unsigned u = __builtin_bit_cast(unsigned, f);
  unsigned r = (u + 0x7FFFu + ((u >> 16) & 1u)) >> 16;
  return (u16)r;
}
__device__ __forceinline__ float bf2f(u16 h) {
  return __builtin_bit_cast(float, ((unsigned)h) << 16);
}
// fast tanh-form GELU: v * sigmoid(v*(1.5957691 + 0.07135481*v^2))
__device__ __forceinline__ float gelu_f(float v) {
  float t = v * v;
  float a = __builtin_fmaf(t, -0.07135481627f, -1.59576912161f);
  float e = __expf(v * a);
  return v * __builtin_amdgcn_rcpf(1.0f + e);
}
// swizzled element index into bf16 LDS array [rows][ld], 16B-chunk XOR swizzle
__device__ __forceinline__ int swz(int row, int col, int ld) {
  return row * ld + ((((col >> 3) ^ (row & 7)) << 3) | (col & 7));
}
__device__ __forceinline__ short8x ldfrag(const u16* s, int row, int kb, int ld) {
  return *(const short8x*)(s + row * ld + (((kb >> 3) ^ (row & 7)) << 3));
}
__device__ __forceinline__ short8x ldg8(const u16* p) { return *(const short8x*)p; }

__device__ __forceinline__ f32x4 MFMA(short8x a, short8x b, f32x4 c) {
  return __builtin_amdgcn_mfma_f32_16x16x32_bf16(
      __builtin_bit_cast(bf16x8, a), __builtin_bit_cast(bf16x8, b), c, 0, 0, 0);
}

// ---------------- weight conversion ----------------
__global__ void cvt_kernel(const float* __restrict__ wqkv, const float* __restrict__ wproj,
                           const float* __restrict__ wfc1, const float* __restrict__ wfc2,
                           const float* __restrict__ c1, const float* __restrict__ c3,
                           const float* __restrict__ c2,
                           u16* oq, u16* op, u16* o1, u16* o2, u16* oc1, u16* oc3,
                           float* ow2r) {
  int i = blockIdx.x * 256 + threadIdx.x;
  if (i < 110592) { float f = wqkv[i]; if (i < 36864) f *= SCALE; oq[i] = f2bf(f); return; }
  i -= 110592;
  if (i < 36864) { op[i] = f2bf(wproj[i]); return; }
  i -= 36864;
  if (i < 147456) { o1[i] = f2bf(wfc1[i]); return; }
  i -= 147456;
  if (i < 147456) {
    // W2 with k-rows permuted to match packed hidden LDS layout:
    // permuted pos P (within 768): g=P>>5, w5=P&31 -> true k = g*32 + (w5&1)*16 + (w5>>1)
    int ocol = i / 768, P = i - ocol * 768;
    int g = P >> 5, w5 = P & 31;
    int H = (g << 5) + ((w5 & 1) << 4) + (w5 >> 1);
    o2[i] = f2bf(wfc2[ocol * 768 + H]); return;
  }
  i -= 147456;
  if (i < 6144) { int r = i / 192, c = i - r * 192; oc1[i] = (r < 24) ? f2bf(c1[r * 192 + c]) : (u16)0; return; }
  i -= 6144;
  if (i < 6144) { int cc = i >> 5, k = i & 31; oc3[i] = (k < 24) ? f2bf(c3[cc * 24 + k]) : (u16)0; return; }
  i -= 6144;
  if (i < 5184) { int t = i / 576, rr = i - t * 576; int ci = rr / 24, co = rr - ci * 24;
                  ow2r[i] = c2[co * 216 + ci * 9 + t]; }
}

// ---------------- LN1 ----------------
__global__ __launch_bounds__(256) void ln1_kernel(const float* __restrict__ x,
                                                  const float* __restrict__ g,
                                                  const float* __restrict__ b,
                                                  u16* __restrict__ nx) {
  const int wid = threadIdx.x >> 6, lane = threadIdx.x & 63;
  const int row = blockIdx.x * 4 + wid;
  const float* xr = x + row * 192;
  float v0 = xr[lane], v1 = xr[lane + 64], v2 = xr[lane + 128];
  float s = v0 + v1 + v2;
  for (int m = 1; m < 64; m <<= 1) s += __shfl_xor(s, m);
  const float mean = s * (1.0f / 192.0f);
  const float d0 = v0 - mean, d1 = v1 - mean, d2 = v2 - mean;
  float q = d0 * d0 + d1 * d1 + d2 * d2;
  for (int m = 1; m < 64; m <<= 1) q += __shfl_xor(q, m);
  const float rstd = rsqrtf(q * (1.0f / 192.0f) + 1e-5f);
  u16* o = nx + row * 192;
  o[lane]       = f2bf(d0 * rstd * g[lane] + b[lane]);
  o[lane + 64]  = f2bf(d1 * rstd * g[lane + 64] + b[lane + 64]);
  o[lane + 128] = f2bf(d2 * rstd * g[lane + 128] + b[lane + 128]);
}

// ---------------- fused shifted-window attention ----------------
__global__ __launch_bounds__(384, 1) void attn_kernel(
    const float* __restrict__ x, const u16* __restrict__ nx,
    const u16* __restrict__ wq, const float* __restrict__ bqkv,
    const float* __restrict__ rel, const u16* __restrict__ wp,
    const float* __restrict__ bproj, float* __restrict__ x1out) {
  __shared__ u16 sU[6 * 64 * 64];   // window tile [64][192] then per-head P [64][64]
  __shared__ u16 sQKV[64 * 576];    // qkv; q-region reused for attn-out
  __shared__ float sRel[225 * 6];
  __shared__ int sG[64];

  const int tid = threadIdx.x, blk = blockIdx.x;
  const int b = blk >> 10, wi = (blk >> 5) & 31, wj = blk & 31;
  const int wv = tid >> 6, lane = tid & 63, lr = lane & 15, hi = lane >> 4;

  for (int i = tid; i < 1350; i += 384) sRel[i] = rel[i];
  if (tid < 64) {
    int si = (wi * 8 + (tid >> 3) + 4) & 255, sj = (wj * 8 + (tid & 7) + 4) & 255;
    sG[tid] = b * 65536 + si * 256 + sj;
  }
  for (int i = tid; i < 64 * 96; i += 384) {
    int r = i / 96, w32 = i - r * 96;
    int si = (wi * 8 + (r >> 3) + 4) & 255, sj = (wj * 8 + (r & 7) + 4) & 255;
    int grow = b * 65536 + si * 256 + sj;
    unsigned v = ((const unsigned*)nx)[grow * 96 + w32];
    ((unsigned*)sU)[r * 96 + ((((w32 >> 2) ^ (r & 7)) << 2) | (w32 & 3))] = v;
  }
  __syncthreads();

  // ---- QKV: [64,192] @ [576,192]^T ----
  for (int nt0 = 0; nt0 < 6; ++nt0) {
    const int ocol = (wv * 6 + nt0) * 16 + lr;
    short8x Bf[6];
#pragma unroll
    for (int kk = 0; kk < 6; ++kk) Bf[kk] = ldg8(wq + ocol * 192 + kk * 32 + hi * 8);
    const float bias = bqkv[ocol] * (ocol < 192 ? SCALE : 1.0f);
#pragma unroll
    for (int mt = 0; mt < 4; ++mt) {
      f32x4 acc = {0.f, 0.f, 0.f, 0.f};
#pragma unroll
      for (int kk = 0; kk < 6; ++kk)
        acc = MFMA(ldfrag(sU, mt * 16 + lr, kk * 32 + hi * 8, 192), Bf[kk], acc);
#pragma unroll
      for (int r = 0; r < 4; ++r)
        sQKV[swz(mt * 16 + hi * 4 + r, ocol, 576)] = f2bf(acc[r] + bias);
    }
  }
  __syncthreads();

  // ---- S = Q K^T + bias + mask, softmax -> P (wave = head) ----
  const int h = wv;
  {
    short8x Aq[4], Bk[4];
#pragma unroll
    for (int t4 = 0; t4 < 4; ++t4) {
      Aq[t4] = ldfrag(sQKV, t4 * 16 + lr, h * 32 + hi * 8, 576);
      Bk[t4] = ldfrag(sQKV, t4 * 16 + lr, 192 + h * 32 + hi * 8, 576);
    }
    f32x4 S[4][4];
#pragma unroll
    for (int mt = 0; mt < 4; ++mt)
#pragma unroll
      for (int nt = 0; nt < 4; ++nt)
        S[mt][nt] = MFMA(Aq[mt], Bk[nt], (f32x4){0.f, 0.f, 0.f, 0.f});

#pragma unroll
    for (int mt = 0; mt < 4; ++mt)
#pragma unroll
      for (int r = 0; r < 4; ++r) {
        const int tI = mt * 16 + hi * 4 + r;
        const int tri = tI >> 3, trj = tI & 7;
        const int ui = wi * 8 + tri, vi = wj * 8 + trj;
        const int rgi = (ui >= 248) + (ui >= 252), cgi = (vi >= 248) + (vi >= 252);
#pragma unroll
        for (int nt = 0; nt < 4; ++nt) {
          const int tJ = nt * 16 + lr;
          const int tci = tJ >> 3, tcj = tJ & 7;
          const int idx = (tri - tci + 7) * 15 + (trj - tcj + 7);
          float v = S[mt][nt][r] + sRel[idx * 6 + h];
          const int uj = wi * 8 + tci, vj = wj * 8 + tcj;
          const int rgj = (uj >= 248) + (uj >= 252), cgj = (vj >= 248) + (vj >= 252);
          if ((rgi != rgj) | (cgi != cgj)) v -= 100.0f;
          S[mt][nt][r] = v;
        }
      }
#pragma unroll
    for (int mt = 0; mt < 4; ++mt)
#pragma unroll
      for (int r = 0; r < 4; ++r) {
        float mx = fmaxf(fmaxf(S[mt][0][r], S[mt][1][r]), fmaxf(S[mt][2][r], S[mt][3][r]));
        mx = fmaxf(mx, __shfl_xor(mx, 1));
        mx = fmaxf(mx, __shfl_xor(mx, 2));
        mx = fmaxf(mx, __shfl_xor(mx, 4));
        mx = fmaxf(mx, __shfl_xor(mx, 8));
        float sm = 0.f;
#pragma unroll
        for (int nt = 0; nt < 4; ++nt) { float e = __expf(S[mt][nt][r] - mx); S[mt][nt][r] = e; sm += e; }
        sm += __shfl_xor(sm, 1); sm += __shfl_xor(sm, 2);
        sm += __shfl_xor(sm, 4); sm += __shfl_xor(sm, 8);
        const float inv = 1.0f / sm;
        const int row = mt * 16 + hi * 4 + r;
#pragma unroll
        for (int nt = 0; nt < 4; ++nt)
          sU[h * 4096 + swz(row, nt * 16 + lr, 64)] = f2bf(S[mt][nt][r] * inv);
      }
  }
  __syncthreads();

  // ---- PV: out[t,d] into sQKV cols [0,192) ----
  {
    const u16* Ph = sU + h * 4096;
#pragma unroll
    for (int nt = 0; nt < 2; ++nt) {
      const int dcol = 384 + h * 32 + nt * 16 + lr;
      f32x4 o[4] = {{0.f,0.f,0.f,0.f},{0.f,0.f,0.f,0.f},{0.f,0.f,0.f,0.f},{0.f,0.f,0.f,0.f}};
#pragma unroll
      for (int kk = 0; kk < 2; ++kk) {
        short8x Bv;
#pragma unroll
        for (int jj = 0; jj < 8; ++jj)
          Bv[jj] = (short)sQKV[swz(kk * 32 + hi * 8 + jj, dcol, 576)];
#pragma unroll
        for (int mt = 0; mt < 4; ++mt)
          o[mt] = MFMA(ldfrag(Ph, mt * 16 + lr, kk * 32 + hi * 8, 64), Bv, o[mt]);
      }
#pragma unroll
      for (int mt = 0; mt < 4; ++mt)
#pragma unroll
        for (int r = 0; r < 4; ++r)
          sQKV[swz(mt * 16 + hi * 4 + r, h * 32 + nt * 16 + lr, 576)] = f2bf(o[mt][r]);
    }
  }
  __syncthreads();

  // ---- proj + residual -> x1 (d_out) ----
  for (int nt0 = 0; nt0 < 2; ++nt0) {
    const int ocol = (wv * 2 + nt0) * 16 + lr;
    short8x Bf[6];
#pragma unroll
    for (int kk = 0; kk < 6; ++kk) Bf[kk] = ldg8(wp + ocol * 192 + kk * 32 + hi * 8);
    const float bb = bproj[ocol];
#pragma unroll
    for (int mt = 0; mt < 4; ++mt) {
      f32x4 acc = {0.f, 0.f, 0.f, 0.f};
#pragma unroll
      for (int kk = 0; kk < 6; ++kk)
        acc = MFMA(ldfrag(sQKV, mt * 16 + lr, kk * 32 + hi * 8, 576), Bf[kk], acc);
#pragma unroll
      for (int r = 0; r < 4; ++r) {
        const int grow = sG[mt * 16 + hi * 4 + r];
        x1out[grow * 192 + ocol] = x[grow * 192 + ocol] + acc[r] + bb;
      }
    }
  }
}

// ---------------- conv1 (1x1, 192->24 padded 32), MFMA ----------------
__global__ __launch_bounds__(256) void conv1_kernel(const u16* __restrict__ nx,
                                                    const u16* __restrict__ w1,
                                                    const float* __restrict__ b1,
                                                    float* __restrict__ y1) {
  const int tid = threadIdx.x, wv = tid >> 6, lane = tid & 63, lr = lane & 15, hi = lane >> 4;
  const int g0 = blockIdx.x * 64;
  const int mt = wv;
  short8x Af[6];
#pragma unroll
  for (int kk = 0; kk < 6; ++kk)
    Af[kk] = ldg8(nx + (g0 + mt * 16 + lr) * 192 + kk * 32 + hi * 8);
  const int bI = g0 >> 16;
  const int hw0 = g0 & 65535;
#pragma unroll
  for (int nt = 0; nt < 2; ++nt) {
    f32x4 acc = {0.f, 0.f, 0.f, 0.f};
#pragma unroll
    for (int kk = 0; kk < 6; ++kk) {
      short8x Bf = ldg8(w1 + (nt * 16 + lr) * 192 + kk * 32 + hi * 8);
      acc = MFMA(Af[kk], Bf, acc);
    }
    const int c = nt * 16 + lr;
    if (c < 24) {
      const float bb = b1[c];
#pragma unroll
      for (int r = 0; r < 4; ++r) {
        const int pix = hw0 + mt * 16 + hi * 4 + r;
        y1[(bI * 24 + c) * 65536 + pix] = acc[r] + bb;
      }
    }
  }
}

// ---------------- conv2 (3x3, 24->24), VALU ----------------
__global__ __launch_bounds__(256) void conv2_kernel(const float* __restrict__ y1,
                                                    const float* __restrict__ w2r,
                                                    const float* __restrict__ cb2,
                                                    u16* __restrict__ y2) {
  const int j = threadIdx.x;
  const int i = blockIdx.x & 255;
  const int b = blockIdx.x >> 8;
  float acc[24];
#pragma unroll
  for (int r = 0; r < 24; ++r) acc[r] = cb2[r];
  const float* base = y1 + b * 24 * 65536;
  for (int t = 0; t < 9; ++t) {
    const int dh = t / 3 - 1, dw = t % 3 - 1;
    const int ii = i + dh, jj = j + dw;
    const bool ok = (ii >= 0) & (ii < 256) & (jj >= 0) & (jj < 256);
    const int offc = ok ? (ii * 256 + jj) : 0;
    const float* wt = w2r + t * 576;
    float v[24];
#pragma unroll
    for (int ci = 0; ci < 24; ++ci) {
      float vv = base[ci * 65536 + offc];
      v[ci] = ok ? vv : 0.0f;
    }
#pragma unroll
    for (int ci = 0; ci < 24; ++ci)
#pragma unroll
      for (int co = 0; co < 24; ++co)
        acc[co] += v[ci] * wt[ci * 24 + co];
  }
  u16* o = y2 + (b * 65536 + i * 256 + j) * 32;
#pragma unroll
  for (int r = 0; r < 24; ++r) o[r] = f2bf(acc[r]);
  ((unsigned long long*)(o + 24))[0] = 0ull;
  ((unsigned long long*)(o + 24))[1] = 0ull;
}

// ---------------- conv3 (1x1, 24->192) + LeakyReLU + pooled sums ----------------
__global__ __launch_bounds__(256) void conv3_kernel(const u16* __restrict__ y2,
                                                    const u16* __restrict__ w3,
                                                    const float* __restrict__ b3,
                                                    u16* __restrict__ y,
                                                    float* __restrict__ pooled) {
  const int tid = threadIdx.x, wv = tid >> 6, lane = tid & 63, lr = lane & 15, hi = lane >> 4;
  const int g0 = blockIdx.x * 64;
  short8x Af[4];
#pragma unroll
  for (int mt = 0; mt < 4; ++mt)
    Af[mt] = ldg8(y2 + (g0 + mt * 16 + lr) * 32 + hi * 8);
  const int bI = g0 >> 16;
#pragma unroll
  for (int nt0 = 0; nt0 < 3; ++nt0) {
    const int c = (wv * 3 + nt0) * 16 + lr;
    short8x Bf = ldg8(w3 + c * 32 + hi * 8);
    const float bb = b3[c];
    float colsum = 0.f;
#pragma unroll
    for (int mt = 0; mt < 4; ++mt) {
      f32x4 acc = {0.f, 0.f, 0.f, 0.f};
      acc = MFMA(Af[mt], Bf, acc);
#pragma unroll
      for (int r = 0; r < 4; ++r) {
        float v = acc[r] + bb;
        v = (v >= 0.f) ? v : 0.2f * v;
        y[(g0 + mt * 16 + hi * 4 + r) * 192 + c] = f2bf(v);
        colsum += v;
      }
    }
    colsum += __shfl_xor(colsum, 16);
    colsum += __shfl_xor(colsum, 32);
    if (hi == 0) atomicAdd(&pooled[bI * 192 + c], colsum);
  }
}

// ---------------- SE gate ----------------
__global__ void se_kernel(const float* __restrict__ pooled, const float* __restrict__ w1,
                          const float* __restrict__ w2, float* __restrict__ wgt) {
  __shared__ float t[24];
  const int b = blockIdx.x, lane = threadIdx.x;
  if (lane < 24) {
    float s = 0.f;
    for (int c = 0; c < 192; ++c) s += pooled[b * 192 + c] * (1.0f / 65536.0f) * w1[lane * 192 + c];
    t[lane] = fmaxf(s, 0.0f);
  }
  __syncthreads();
  for (int c = lane; c < 192; c += 64) {
    float s = 0.f;
#pragma unroll
    for (int r = 0; r < 24; ++r) s += t[r] * w2[c * 24 + r];
    wgt[b * 192 + c] = 1.0f / (1.0f + __expf(-s));
  }
}

// ---------------- fused LN2 + MLP + residual + LCE add ----------------
// 64 rows/block, hidden processed in 4 chunks of 192 with double-buffered LDS.
// LDS = 24 + 2*24 = 72 KB -> 2 blocks/CU.
__global__ __launch_bounds__(384, 3) void mlp_kernel(
    const float* x1, const float* __restrict__ g2, const float* __restrict__ b2,
    const u16* __restrict__ w1m, const float* __restrict__ bf1,
    const u16* __restrict__ w2m, const float* __restrict__ bf2,
    const u16* __restrict__ y, const float* __restrict__ wgt, float* out) {
  __shared__ u16 sN[64 * 192];
  __shared__ u16 sH[2][64 * 192];
  const int tid = threadIdx.x, wv = tid >> 6, lane = tid & 63, lr = lane & 15, hi = lane >> 4;
  const int g0 = blockIdx.x * 64;

  for (int row = wv; row < 64; row += 6) {
    const float* xr = x1 + (g0 + row) * 192;
    float v0 = xr[lane], v1 = xr[lane + 64], v2 = xr[lane + 128];
    float s = v0 + v1 + v2;
    for (int m = 1; m < 64; m <<= 1) s += __shfl_xor(s, m);
    const float mean = s * (1.0f / 192.0f);
    const float d0 = v0 - mean, d1 = v1 - mean, d2 = v2 - mean;
    float q = d0 * d0 + d1 * d1 + d2 * d2;
    for (int m = 1; m < 64; m <<= 1) q += __shfl_xor(q, m);
    const float rstd = rsqrtf(q * (1.0f / 192.0f) + 1e-5f);
    sN[swz(row, lane, 192)]       = f2bf(d0 * rstd * g2[lane] + b2[lane]);
    sN[swz(row, lane + 64, 192)]  = f2bf(d1 * rstd * g2[lane + 64] + b2[lane + 64]);
    sN[swz(row, lane + 128, 192)] = f2bf(d2 * rstd * g2[lane + 128] + b2[lane + 128]);
  }
  __syncthreads();

  // FC1 for hidden chunk c -> sH[buf]; wave owns 32 hidden cols of the chunk.
  auto fc1 = [&](int c, int buf) {
    const int base = c * 192 + wv * 32;
    f32x4 a1[4][2] = {};
#pragma unroll
    for (int kk = 0; kk < 6; ++kk) {
      short8x B0 = ldg8(w1m + (base + lr) * 192 + kk * 32 + hi * 8);
      short8x B1 = ldg8(w1m + (base + 16 + lr) * 192 + kk * 32 + hi * 8);
#pragma unroll
      for (int mt = 0; mt < 4; ++mt) {
        short8x Af = ldfrag(sN, mt * 16 + lr, kk * 32 + hi * 8, 192);
        a1[mt][0] = MFMA(Af, B0, a1[mt][0]);
        a1[mt][1] = MFMA(Af, B1, a1[mt][1]);
      }
    }
    const float bb0 = bf1[base + lr], bb1 = bf1[base + 16 + lr];
    const int p = wv * 32 + 2 * lr;  // packed (even) position within chunk
#pragma unroll
    for (int mt = 0; mt < 4; ++mt)
#pragma unroll
      for (int r = 0; r < 4; ++r) {
        float v0 = gelu_f(a1[mt][0][r] + bb0);
        float v1 = gelu_f(a1[mt][1][r] + bb1);
        unsigned pk = (unsigned)f2bf(v0) | ((unsigned)f2bf(v1) << 16);
        *(unsigned*)&sH[buf][swz(mt * 16 + hi * 4 + r, p, 192)] = pk;
      }
  };

  fc1(0, 0);
  __syncthreads();

  f32x4 acc[4][2] = {};  // FC2 accumulators (wave owns out cols wv*32..+32)
  for (int c = 0; c < 4; ++c) {
    if (c < 3) fc1(c + 1, (c + 1) & 1);
    const u16* Hb = sH[c & 1];
#pragma unroll
    for (int kk = 0; kk < 6; ++kk) {
      short8x B0 = ldg8(w2m + (wv * 32 + lr) * 768 + c * 192 + kk * 32 + hi * 8);
      short8x B1 = ldg8(w2m + (wv * 32 + 16 + lr) * 768 + c * 192 + kk * 32 + hi * 8);
#pragma unroll
      for (int mt = 0; mt < 4; ++mt) {
        short8x Af = ldfrag(Hb, mt * 16 + lr, kk * 32 + hi * 8, 192);
        acc[mt][0] = MFMA(Af, B0, acc[mt][0]);
        acc[mt][1] = MFMA(Af, B1, acc[mt][1]);
      }
    }
    __syncthreads();
  }

  const int bI = g0 >> 16;
#pragma unroll
  for (int nt = 0; nt < 2; ++nt) {
    const int ocol = wv * 32 + nt * 16 + lr;
    const float bb = bf2[ocol];
    const float wg = wgt[bI * 192 + ocol];
#pragma unroll
    for (int mt = 0; mt < 4; ++mt)
#pragma unroll
      for (int r = 0; r < 4; ++r) {
        const int grow = g0 + mt * 16 + hi * 4 + r;
        const float lc = bf2f(y[grow * 192 + ocol]) * wg;
        out[grow * 192 + ocol] = x1[grow * 192 + ocol] + acc[mt][nt][r] + bb + lc;
      }
  }
}

extern "C" void kernel_launch(void* const* d_in, const int* in_sizes, int n_in,
                              void* d_out, int out_size, void* d_ws, size_t ws_size,
                              hipStream_t stream) {
  const float* x     = (const float*)d_in[0];
  const float* ln1g  = (const float*)d_in[1];
  const float* ln1b  = (const float*)d_in[2];
  const float* wqkv  = (const float*)d_in[3];
  const float* bqkv  = (const float*)d_in[4];
  const float* rel   = (const float*)d_in[5];
  const float* wproj = (const float*)d_in[6];
  const float* bproj = (const float*)d_in[7];
  const float* ln2g  = (const float*)d_in[8];
  const float* ln2b  = (const float*)d_in[9];
  const float* wfc1  = (const float*)d_in[10];
  const float* bfc1  = (const float*)d_in[11];
  const float* wfc2  = (const float*)d_in[12];
  const float* bfc2  = (const float*)d_in[13];
  const float* c1w   = (const float*)d_in[14];
  const float* c1b   = (const float*)d_in[15];
  const float* c2w   = (const float*)d_in[16];
  const float* c2b   = (const float*)d_in[17];
  const float* c3w   = (const float*)d_in[18];
  const float* c3b   = (const float*)d_in[19];
  const float* sew1  = (const float*)d_in[20];
  const float* sew2  = (const float*)d_in[21];

  char* ws = (char*)d_ws;
  u16*   nx   = (u16*)(ws + 0);
  float* y1   = (float*)(ws + 100663296);
  u16*   y2   = (u16*)(ws + 125829120);
  u16*   yb   = (u16*)(ws + 142606336);
  u16*   wq   = (u16*)(ws + 243269632);
  u16*   wp   = (u16*)(ws + 243490816);
  u16*   w1m  = (u16*)(ws + 243564544);
  u16*   w2m  = (u16*)(ws + 243859456);
  u16*   cw1  = (u16*)(ws + 244154368);
  u16*   cw3  = (u16*)(ws + 244166656);
  float* w2r  = (float*)(ws + 244178944);
  float* pool = (float*)(ws + 244199680);
  float* wgt  = (float*)(ws + 244202752);
  float* out  = (float*)d_out;

  hipMemsetAsync(pool, 0, 3072, stream);
  cvt_kernel<<<1797, 256, 0, stream>>>(wqkv, wproj, wfc1, wfc2, c1w, c3w, c2w,
                                       wq, wp, w1m, w2m, cw1, cw3, w2r);
  ln1_kernel<<<65536, 256, 0, stream>>>(x, ln1g, ln1b, nx);
  attn_kernel<<<4096, 384, 0, stream>>>(x, nx, wq, bqkv, rel, wp, bproj, out);
  conv1_kernel<<<4096, 256, 0, stream>>>(nx, cw1, c1b, y1);
  conv2_kernel<<<1024, 256, 0, stream>>>(y1, w2r, c2b, y2);
  conv3_kernel<<<4096, 256, 0, stream>>>(y2, cw3, c3b, yb, pool);
  se_kernel<<<4, 64, 0, stream>>>(pool, sew1, sew2, wgt);
  mlp_kernel<<<4096, 384, 0, stream>>>(out, ln2g, ln2b, w1m, bfc1, w2m, bfc2, yb, wgt, out);
}

// Round 3
// 1023.849 us; speedup vs baseline: 1.3040x; 1.3040x over previous
//
#include <hip/hip_runtime.h>
#include <hip/hip_bf16.h>

typedef unsigned short u16;
typedef __attribute__((ext_vector_type(8))) short short8x;
typedef __attribute__((ext_vector_type(4))) float f32x4;
typedef __bf16 bf16x8 __attribute__((ext_vector_type(8)));

#define SCALE 0.17677669529663687f

__device__ __forceinline__ u16 f2bf(float f) {
  unsigned u = __builtin_bit_cast(unsigned, f);
  unsigned r = (u + 0x7FFFu + ((u >> 16) & 1u)) >> 16;
  return (u16)r;
}
__device__ __forceinline__ float bf2f(u16 h) {
  return __builtin_bit_cast(float, ((unsigned)h) << 16);
}
// fast tanh-form GELU: v * sigmoid(v*(1.5957691 + 0.07135481*v^2))
__device__ __forceinline__ float gelu_f(float v) {
  float t = v * v;
  float a = __builtin_fmaf(t, -0.07135481627f, -1.59576912161f);
  float e = __expf(v * a);
  return v * __builtin_amdgcn_rcpf(1.0f + e);
}
// swizzled element index into bf16 LDS array [rows][ld], 16B-chunk XOR swizzle
__device__ __forceinline__ int swz(int row, int col, int ld) {
  return row * ld + ((((col >> 3) ^ (row & 7)) << 3) | (col & 7));
}
__device__ __forceinline__ short8x ldfrag(const u16* s, int row, int kb, int ld) {
  return *(const short8x*)(s + row * ld + (((kb >> 3) ^ (row & 7)) << 3));
}
__device__ __forceinline__ short8x ldg8(const u16* p) { return *(const short8x*)p; }

__device__ __forceinline__ f32x4 MFMA(short8x a, short8x b, f32x4 c) {
  return __builtin_amdgcn_mfma_f32_16x16x32_bf16(
      __builtin_bit_cast(bf16x8, a), __builtin_bit_cast(bf16x8, b), c, 0, 0, 0);
}

// ---------------- weight conversion ----------------
__global__ void cvt_kernel(const float* __restrict__ wqkv, const float* __restrict__ wproj,
                           const float* __restrict__ wfc1, const float* __restrict__ wfc2,
                           const float* __restrict__ c1, const float* __restrict__ c3,
                           const float* __restrict__ c2,
                           u16* oq, u16* op, u16* o1, u16* o2, u16* oc1, u16* oc3,
                           float* ow2r) {
  int i = blockIdx.x * 256 + threadIdx.x;
  if (i < 110592) { float f = wqkv[i]; if (i < 36864) f *= SCALE; oq[i] = f2bf(f); return; }
  i -= 110592;
  if (i < 36864) { op[i] = f2bf(wproj[i]); return; }
  i -= 36864;
  if (i < 147456) { o1[i] = f2bf(wfc1[i]); return; }
  i -= 147456;
  if (i < 147456) { o2[i] = f2bf(wfc2[i]); return; }
  i -= 147456;
  if (i < 6144) { int r = i / 192, c = i - r * 192; oc1[i] = (r < 24) ? f2bf(c1[r * 192 + c]) : (u16)0; return; }
  i -= 6144;
  if (i < 6144) { int cc = i >> 5, k = i & 31; oc3[i] = (k < 24) ? f2bf(c3[cc * 24 + k]) : (u16)0; return; }
  i -= 6144;
  if (i < 5184) { int t = i / 576, rr = i - t * 576; int ci = rr / 24, co = rr - ci * 24;
                  ow2r[i] = c2[co * 216 + ci * 9 + t]; }
}

// ---------------- LN1 ----------------
__global__ __launch_bounds__(256) void ln1_kernel(const float* __restrict__ x,
                                                  const float* __restrict__ g,
                                                  const float* __restrict__ b,
                                                  u16* __restrict__ nx) {
  const int wid = threadIdx.x >> 6, lane = threadIdx.x & 63;
  const int row = blockIdx.x * 4 + wid;
  const float* xr = x + row * 192;
  float v0 = xr[lane], v1 = xr[lane + 64], v2 = xr[lane + 128];
  float s = v0 + v1 + v2;
  for (int m = 1; m < 64; m <<= 1) s += __shfl_xor(s, m);
  const float mean = s * (1.0f / 192.0f);
  const float d0 = v0 - mean, d1 = v1 - mean, d2 = v2 - mean;
  float q = d0 * d0 + d1 * d1 + d2 * d2;
  for (int m = 1; m < 64; m <<= 1) q += __shfl_xor(q, m);
  const float rstd = rsqrtf(q * (1.0f / 192.0f) + 1e-5f);
  u16* o = nx + row * 192;
  o[lane]       = f2bf(d0 * rstd * g[lane] + b[lane]);
  o[lane + 64]  = f2bf(d1 * rstd * g[lane + 64] + b[lane + 64]);
  o[lane + 128] = f2bf(d2 * rstd * g[lane + 128] + b[lane + 128]);
}

// ---------------- fused shifted-window attention (12 waves) ----------------
__global__ __launch_bounds__(768, 3) void attn_kernel(
    const float* __restrict__ x, const u16* __restrict__ nx,
    const u16* __restrict__ wq, const float* __restrict__ bqkv,
    const float* __restrict__ rel, const u16* __restrict__ wp,
    const float* __restrict__ bproj, float* __restrict__ x1out) {
  __shared__ u16 sU[6 * 64 * 64];   // window tile [64][192] then per-head P [64][64]
  __shared__ u16 sQKV[64 * 576];    // qkv; q-region reused for attn-out
  __shared__ float sRel[225 * 6];
  __shared__ int sG[64];

  const int tid = threadIdx.x, blk = blockIdx.x;
  const int b = blk >> 10, wi = (blk >> 5) & 31, wj = blk & 31;
  const int wv = tid >> 6, lane = tid & 63, lr = lane & 15, hi = lane >> 4;

  for (int i = tid; i < 1350; i += 768) sRel[i] = rel[i];
  if (tid < 64) {
    int si = (wi * 8 + (tid >> 3) + 4) & 255, sj = (wj * 8 + (tid & 7) + 4) & 255;
    sG[tid] = b * 65536 + si * 256 + sj;
  }
  for (int i = tid; i < 64 * 96; i += 768) {
    int r = i / 96, w32 = i - r * 96;
    int si = (wi * 8 + (r >> 3) + 4) & 255, sj = (wj * 8 + (r & 7) + 4) & 255;
    int grow = b * 65536 + si * 256 + sj;
    unsigned v = ((const unsigned*)nx)[grow * 96 + w32];
    ((unsigned*)sU)[r * 96 + ((((w32 >> 2) ^ (r & 7)) << 2) | (w32 & 3))] = v;
  }
  __syncthreads();

  // ---- QKV: [64,192] @ [576,192]^T ; wave owns 3 output ntiles ----
  for (int nt0 = 0; nt0 < 3; ++nt0) {
    const int ocol = (wv * 3 + nt0) * 16 + lr;
    short8x Bf[6];
#pragma unroll
    for (int kk = 0; kk < 6; ++kk) Bf[kk] = ldg8(wq + ocol * 192 + kk * 32 + hi * 8);
    const float bias = bqkv[ocol] * (ocol < 192 ? SCALE : 1.0f);
#pragma unroll
    for (int mt = 0; mt < 4; ++mt) {
      f32x4 acc = {0.f, 0.f, 0.f, 0.f};
#pragma unroll
      for (int kk = 0; kk < 6; ++kk)
        acc = MFMA(ldfrag(sU, mt * 16 + lr, kk * 32 + hi * 8, 192), Bf[kk], acc);
#pragma unroll
      for (int r = 0; r < 4; ++r)
        sQKV[swz(mt * 16 + hi * 4 + r, ocol, 576)] = f2bf(acc[r] + bias);
    }
  }
  __syncthreads();

  // ---- S = Q K^T + bias + mask, softmax -> P (2 waves per head) ----
  const int h = wv >> 1, half = wv & 1;
  {
    short8x Aq[2], Bk[4];
#pragma unroll
    for (int i2 = 0; i2 < 2; ++i2)
      Aq[i2] = ldfrag(sQKV, (half * 2 + i2) * 16 + lr, h * 32 + hi * 8, 576);
#pragma unroll
    for (int t4 = 0; t4 < 4; ++t4)
      Bk[t4] = ldfrag(sQKV, t4 * 16 + lr, 192 + h * 32 + hi * 8, 576);
    f32x4 S[2][4];
#pragma unroll
    for (int i2 = 0; i2 < 2; ++i2)
#pragma unroll
      for (int nt = 0; nt < 4; ++nt)
        S[i2][nt] = MFMA(Aq[i2], Bk[nt], (f32x4){0.f, 0.f, 0.f, 0.f});

#pragma unroll
    for (int i2 = 0; i2 < 2; ++i2)
#pragma unroll
      for (int r = 0; r < 4; ++r) {
        const int tI = (half * 2 + i2) * 16 + hi * 4 + r;
        const int tri = tI >> 3, trj = tI & 7;
        const int ui = wi * 8 + tri, vi = wj * 8 + trj;
        const int rgi = (ui >= 248) + (ui >= 252), cgi = (vi >= 248) + (vi >= 252);
#pragma unroll
        for (int nt = 0; nt < 4; ++nt) {
          const int tJ = nt * 16 + lr;
          const int tci = tJ >> 3, tcj = tJ & 7;
          const int idx = (tri - tci + 7) * 15 + (trj - tcj + 7);
          float v = S[i2][nt][r] + sRel[idx * 6 + h];
          const int uj = wi * 8 + tci, vj = wj * 8 + tcj;
          const int rgj = (uj >= 248) + (uj >= 252), cgj = (vj >= 248) + (vj >= 252);
          if ((rgi != rgj) | (cgi != cgj)) v -= 100.0f;
          S[i2][nt][r] = v;
        }
      }
#pragma unroll
    for (int i2 = 0; i2 < 2; ++i2)
#pragma unroll
      for (int r = 0; r < 4; ++r) {
        float mx = fmaxf(fmaxf(S[i2][0][r], S[i2][1][r]), fmaxf(S[i2][2][r], S[i2][3][r]));
        mx = fmaxf(mx, __shfl_xor(mx, 1));
        mx = fmaxf(mx, __shfl_xor(mx, 2));
        mx = fmaxf(mx, __shfl_xor(mx, 4));
        mx = fmaxf(mx, __shfl_xor(mx, 8));
        float sm = 0.f;
#pragma unroll
        for (int nt = 0; nt < 4; ++nt) { float e = __expf(S[i2][nt][r] - mx); S[i2][nt][r] = e; sm += e; }
        sm += __shfl_xor(sm, 1); sm += __shfl_xor(sm, 2);
        sm += __shfl_xor(sm, 4); sm += __shfl_xor(sm, 8);
        const float inv = 1.0f / sm;
        const int row = (half * 2 + i2) * 16 + hi * 4 + r;
#pragma unroll
        for (int nt = 0; nt < 4; ++nt)
          sU[h * 4096 + swz(row, nt * 16 + lr, 64)] = f2bf(S[i2][nt][r] * inv);
      }
  }
  __syncthreads();

  // ---- PV: wave = (head, nt) -> out cols into sQKV q-region ----
  {
    const u16* Ph = sU + h * 4096;
    const int nt = half;
    const int dcol = 384 + h * 32 + nt * 16 + lr;
    f32x4 o[4] = {{0.f,0.f,0.f,0.f},{0.f,0.f,0.f,0.f},{0.f,0.f,0.f,0.f},{0.f,0.f,0.f,0.f}};
#pragma unroll
    for (int kk = 0; kk < 2; ++kk) {
      short8x Bv;
#pragma unroll
      for (int jj = 0; jj < 8; ++jj)
        Bv[jj] = (short)sQKV[swz(kk * 32 + hi * 8 + jj, dcol, 576)];
#pragma unroll
      for (int mt = 0; mt < 4; ++mt)
        o[mt] = MFMA(ldfrag(Ph, mt * 16 + lr, kk * 32 + hi * 8, 64), Bv, o[mt]);
    }
    __syncthreads();  // P fully consumed; and ensures all reads of q-region done earlier
#pragma unroll
    for (int mt = 0; mt < 4; ++mt)
#pragma unroll
      for (int r = 0; r < 4; ++r)
        sQKV[swz(mt * 16 + hi * 4 + r, h * 32 + nt * 16 + lr, 576)] = f2bf(o[mt][r]);
  }
  __syncthreads();

  // ---- proj + residual -> x1 (d_out); wave owns 1 ntile ----
  {
    const int ocol = wv * 16 + lr;
    short8x Bf[6];
#pragma unroll
    for (int kk = 0; kk < 6; ++kk) Bf[kk] = ldg8(wp + ocol * 192 + kk * 32 + hi * 8);
    const float bb = bproj[ocol];
#pragma unroll
    for (int mt = 0; mt < 4; ++mt) {
      f32x4 acc = {0.f, 0.f, 0.f, 0.f};
#pragma unroll
      for (int kk = 0; kk < 6; ++kk)
        acc = MFMA(ldfrag(sQKV, mt * 16 + lr, kk * 32 + hi * 8, 576), Bf[kk], acc);
#pragma unroll
      for (int r = 0; r < 4; ++r) {
        const int grow = sG[mt * 16 + hi * 4 + r];
        x1out[grow * 192 + ocol] = x[grow * 192 + ocol] + acc[r] + bb;
      }
    }
  }
}

// ---------------- conv1 (1x1, 192->24 padded 32), MFMA ----------------
__global__ __launch_bounds__(256) void conv1_kernel(const u16* __restrict__ nx,
                                                    const u16* __restrict__ w1,
                                                    const float* __restrict__ b1,
                                                    float* __restrict__ y1) {
  const int tid = threadIdx.x, wv = tid >> 6, lane = tid & 63, lr = lane & 15, hi = lane >> 4;
  const int g0 = blockIdx.x * 64;
  const int mt = wv;
  short8x Af[6];
#pragma unroll
  for (int kk = 0; kk < 6; ++kk)
    Af[kk] = ldg8(nx + (g0 + mt * 16 + lr) * 192 + kk * 32 + hi * 8);
  const int bI = g0 >> 16;
  const int hw0 = g0 & 65535;
#pragma unroll
  for (int nt = 0; nt < 2; ++nt) {
    f32x4 acc = {0.f, 0.f, 0.f, 0.f};
#pragma unroll
    for (int kk = 0; kk < 6; ++kk) {
      short8x Bf = ldg8(w1 + (nt * 16 + lr) * 192 + kk * 32 + hi * 8);
      acc = MFMA(Af[kk], Bf, acc);
    }
    const int c = nt * 16 + lr;
    if (c < 24) {
      const float bb = b1[c];
#pragma unroll
      for (int r = 0; r < 4; ++r) {
        const int pix = hw0 + mt * 16 + hi * 4 + r;
        y1[(bI * 24 + c) * 65536 + pix] = acc[r] + bb;
      }
    }
  }
}

// ---------------- conv2 (3x3, 24->24), VALU ----------------
__global__ __launch_bounds__(256) void conv2_kernel(const float* __restrict__ y1,
                                                    const float* __restrict__ w2r,
                                                    const float* __restrict__ cb2,
                                                    u16* __restrict__ y2) {
  const int j = threadIdx.x;
  const int i = blockIdx.x & 255;
  const int b = blockIdx.x >> 8;
  float acc[24];
#pragma unroll
  for (int r = 0; r < 24; ++r) acc[r] = cb2[r];
  const float* base = y1 + b * 24 * 65536;
  for (int t = 0; t < 9; ++t) {
    const int dh = t / 3 - 1, dw = t % 3 - 1;
    const int ii = i + dh, jj = j + dw;
    const bool ok = (ii >= 0) & (ii < 256) & (jj >= 0) & (jj < 256);
    const int offc = ok ? (ii * 256 + jj) : 0;
    const float* wt = w2r + t * 576;
    float v[24];
#pragma unroll
    for (int ci = 0; ci < 24; ++ci) {
      float vv = base[ci * 65536 + offc];
      v[ci] = ok ? vv : 0.0f;
    }
#pragma unroll
    for (int ci = 0; ci < 24; ++ci)
#pragma unroll
      for (int co = 0; co < 24; ++co)
        acc[co] += v[ci] * wt[ci * 24 + co];
  }
  u16* o = y2 + (b * 65536 + i * 256 + j) * 32;
#pragma unroll
  for (int r = 0; r < 24; ++r) o[r] = f2bf(acc[r]);
  ((unsigned long long*)(o + 24))[0] = 0ull;
  ((unsigned long long*)(o + 24))[1] = 0ull;
}

// ---------------- conv3 (1x1, 24->192) + LeakyReLU + pooled sums ----------------
__global__ __launch_bounds__(256) void conv3_kernel(const u16* __restrict__ y2,
                                                    const u16* __restrict__ w3,
                                                    const float* __restrict__ b3,
                                                    u16* __restrict__ y,
                                                    float* __restrict__ pooled) {
  const int tid = threadIdx.x, wv = tid >> 6, lane = tid & 63, lr = lane & 15, hi = lane >> 4;
  const int g0 = blockIdx.x * 64;
  short8x Af[4];
#pragma unroll
  for (int mt = 0; mt < 4; ++mt)
    Af[mt] = ldg8(y2 + (g0 + mt * 16 + lr) * 32 + hi * 8);
  const int bI = g0 >> 16;
#pragma unroll
  for (int nt0 = 0; nt0 < 3; ++nt0) {
    const int c = (wv * 3 + nt0) * 16 + lr;
    short8x Bf = ldg8(w3 + c * 32 + hi * 8);
    const float bb = b3[c];
    float colsum = 0.f;
#pragma unroll
    for (int mt = 0; mt < 4; ++mt) {
      f32x4 acc = {0.f, 0.f, 0.f, 0.f};
      acc = MFMA(Af[mt], Bf, acc);
#pragma unroll
      for (int r = 0; r < 4; ++r) {
        float v = acc[r] + bb;
        v = (v >= 0.f) ? v : 0.2f * v;
        y[(g0 + mt * 16 + hi * 4 + r) * 192 + c] = f2bf(v);
        colsum += v;
      }
    }
    colsum += __shfl_xor(colsum, 16);
    colsum += __shfl_xor(colsum, 32);
    if (hi == 0) atomicAdd(&pooled[bI * 192 + c], colsum);
  }
}

// ---------------- SE gate ----------------
__global__ void se_kernel(const float* __restrict__ pooled, const float* __restrict__ w1,
                          const float* __restrict__ w2, float* __restrict__ wgt) {
  __shared__ float t[24];
  const int b = blockIdx.x, lane = threadIdx.x;
  if (lane < 24) {
    float s = 0.f;
    for (int c = 0; c < 192; ++c) s += pooled[b * 192 + c] * (1.0f / 65536.0f) * w1[lane * 192 + c];
    t[lane] = fmaxf(s, 0.0f);
  }
  __syncthreads();
  for (int c = lane; c < 192; c += 64) {
    float s = 0.f;
#pragma unroll
    for (int r = 0; r < 24; ++r) s += t[r] * w2[c * 24 + r];
    wgt[b * 192 + c] = 1.0f / (1.0f + __expf(-s));
  }
}

// ---------------- fused LN2 + MLP + residual + LCE add ----------------
// 64 rows/block, 12 waves, single sH buffer. LDS = 24 + 24 = 48 KB -> 2 blocks/CU.
__global__ __launch_bounds__(768, 6) void mlp_kernel(
    const float* x1, const float* __restrict__ g2, const float* __restrict__ b2,
    const u16* __restrict__ w1m, const float* __restrict__ bf1,
    const u16* __restrict__ w2m, const float* __restrict__ bf2,
    const u16* __restrict__ y, const float* __restrict__ wgt, float* out) {
  __shared__ u16 sN[64 * 192];
  __shared__ u16 sH[64 * 192];
  const int tid = threadIdx.x, wv = tid >> 6, lane = tid & 63, lr = lane & 15, hi = lane >> 4;
  const int g0 = blockIdx.x * 64;

  for (int row = wv; row < 64; row += 12) {
    const float* xr = x1 + (g0 + row) * 192;
    float v0 = xr[lane], v1 = xr[lane + 64], v2 = xr[lane + 128];
    float s = v0 + v1 + v2;
    for (int m = 1; m < 64; m <<= 1) s += __shfl_xor(s, m);
    const float mean = s * (1.0f / 192.0f);
    const float d0 = v0 - mean, d1 = v1 - mean, d2 = v2 - mean;
    float q = d0 * d0 + d1 * d1 + d2 * d2;
    for (int m = 1; m < 64; m <<= 1) q += __shfl_xor(q, m);
    const float rstd = rsqrtf(q * (1.0f / 192.0f) + 1e-5f);
    sN[swz(row, lane, 192)]       = f2bf(d0 * rstd * g2[lane] + b2[lane]);
    sN[swz(row, lane + 64, 192)]  = f2bf(d1 * rstd * g2[lane + 64] + b2[lane + 64]);
    sN[swz(row, lane + 128, 192)] = f2bf(d2 * rstd * g2[lane + 128] + b2[lane + 128]);
  }
  __syncthreads();

  f32x4 acc[4] = {};  // FC2 accumulators: wave owns out cols wv*16..+16
  for (int c = 0; c < 4; ++c) {
    // FC1 for hidden chunk c: wave owns 16 hidden cols
    const int hcol = c * 192 + wv * 16 + lr;
    f32x4 a1[4] = {};
#pragma unroll
    for (int kk = 0; kk < 6; ++kk) {
      short8x B = ldg8(w1m + hcol * 192 + kk * 32 + hi * 8);
#pragma unroll
      for (int mt = 0; mt < 4; ++mt)
        a1[mt] = MFMA(ldfrag(sN, mt * 16 + lr, kk * 32 + hi * 8, 192), B, a1[mt]);
    }
    if (c) __syncthreads();  // fc2(c-1) readers done before overwriting sH
    const float bb1 = bf1[hcol];
#pragma unroll
    for (int mt = 0; mt < 4; ++mt)
#pragma unroll
      for (int r = 0; r < 4; ++r)
        sH[swz(mt * 16 + hi * 4 + r, wv * 16 + lr, 192)] = f2bf(gelu_f(a1[mt][r] + bb1));
    __syncthreads();
    // FC2 partial over this chunk's K
#pragma unroll
    for (int kk = 0; kk < 6; ++kk) {
      short8x B = ldg8(w2m + (wv * 16 + lr) * 768 + c * 192 + kk * 32 + hi * 8);
#pragma unroll
      for (int mt = 0; mt < 4; ++mt)
        acc[mt] = MFMA(ldfrag(sH, mt * 16 + lr, kk * 32 + hi * 8, 192), B, acc[mt]);
    }
  }

  const int bI = g0 >> 16;
  const int ocol = wv * 16 + lr;
  const float bb = bf2[ocol];
  const float wg = wgt[bI * 192 + ocol];
#pragma unroll
  for (int mt = 0; mt < 4; ++mt)
#pragma unroll
    for (int r = 0; r < 4; ++r) {
      const int grow = g0 + mt * 16 + hi * 4 + r;
      const float lc = bf2f(y[grow * 192 + ocol]) * wg;
      out[grow * 192 + ocol] = x1[grow * 192 + ocol] + acc[mt][r] + bb + lc;
    }
}

extern "C" void kernel_launch(void* const* d_in, const int* in_sizes, int n_in,
                              void* d_out, int out_size, void* d_ws, size_t ws_size,
                              hipStream_t stream) {
  const float* x     = (const float*)d_in[0];
  const float* ln1g  = (const float*)d_in[1];
  const float* ln1b  = (const float*)d_in[2];
  const float* wqkv  = (const float*)d_in[3];
  const float* bqkv  = (const float*)d_in[4];
  const float* rel   = (const float*)d_in[5];
  const float* wproj = (const float*)d_in[6];
  const float* bproj = (const float*)d_in[7];
  const float* ln2g  = (const float*)d_in[8];
  const float* ln2b  = (const float*)d_in[9];
  const float* wfc1  = (const float*)d_in[10];
  const float* bfc1  = (const float*)d_in[11];
  const float* wfc2  = (const float*)d_in[12];
  const float* bfc2  = (const float*)d_in[13];
  const float* c1w   = (const float*)d_in[14];
  const float* c1b   = (const float*)d_in[15];
  const float* c2w   = (const float*)d_in[16];
  const float* c2b   = (const float*)d_in[17];
  const float* c3w   = (const float*)d_in[18];
  const float* c3b   = (const float*)d_in[19];
  const float* sew1  = (const float*)d_in[20];
  const float* sew2  = (const float*)d_in[21];

  char* ws = (char*)d_ws;
  u16*   nx   = (u16*)(ws + 0);
  float* y1   = (float*)(ws + 100663296);
  u16*   y2   = (u16*)(ws + 125829120);
  u16*   yb   = (u16*)(ws + 142606336);
  u16*   wq   = (u16*)(ws + 243269632);
  u16*   wp   = (u16*)(ws + 243490816);
  u16*   w1m  = (u16*)(ws + 243564544);
  u16*   w2m  = (u16*)(ws + 243859456);
  u16*   cw1  = (u16*)(ws + 244154368);
  u16*   cw3  = (u16*)(ws + 244166656);
  float* w2r  = (float*)(ws + 244178944);
  float* pool = (float*)(ws + 244199680);
  float* wgt  = (float*)(ws + 244202752);
  float* out  = (float*)d_out;

  hipMemsetAsync(pool, 0, 3072, stream);
  cvt_kernel<<<1797, 256, 0, stream>>>(wqkv, wproj, wfc1, wfc2, c1w, c3w, c2w,
                                       wq, wp, w1m, w2m, cw1, cw3, w2r);
  ln1_kernel<<<65536, 256, 0, stream>>>(x, ln1g, ln1b, nx);
  attn_kernel<<<4096, 768, 0, stream>>>(x, nx, wq, bqkv, rel, wp, bproj, out);
  conv1_kernel<<<4096, 256, 0, stream>>>(nx, cw1, c1b, y1);
  conv2_kernel<<<1024, 256, 0, stream>>>(y1, w2r, c2b, y2);
  conv3_kernel<<<4096, 256, 0, stream>>>(y2, cw3, c3b, yb, pool);
  se_kernel<<<4, 64, 0, stream>>>(pool, sew1, sew2, wgt);
  mlp_kernel<<<4096, 768, 0, stream>>>(out, ln2g, ln2b, w1m, bfc1, w2m, bfc2, yb, wgt, out);
}